// Round 8
// baseline (414.690 us; speedup 1.0000x reference)
//
#include <hip/hip_runtime.h>

#define HW 3136
#define NPOS 12845056   // 16*256*3136

__device__ __forceinline__ unsigned fkey(float f) {
  unsigned u = __float_as_uint(f);
  return (u & 0x80000000u) ? ~u : (u | 0x80000000u);
}
__device__ __forceinline__ float funkey(unsigned u) {
  return __uint_as_float((u & 0x80000000u) ? (u & 0x7FFFFFFFu) : ~u);
}
__device__ __forceinline__ float spikef(float x) {
  return fminf(fmaxf(rintf(x), 0.0f), 4.0f);
}

// ---------------- Kernel 1: transposes + audio pre-projection + init ----------------
// w1t: [k 256][j 128]   w2t: [k2 128][j2 64]
__global__ __launch_bounds__(256) void prep_kernel(
    const float* __restrict__ audio, const float* __restrict__ w1,
    const float* __restrict__ b1, const float* __restrict__ w2,
    float* __restrict__ a_pre, float* __restrict__ w1t,
    float* __restrict__ w2t, float* __restrict__ pool,
    unsigned* __restrict__ mm)
{
  __shared__ float au[256];
  const int bx = blockIdx.x, t = threadIdx.x;
  if (bx < 128) {                       // w1 visual half -> w1t[k][j]
    int idx = bx * 256 + t;             // 32768
    int c = idx >> 7, j = idx & 127;
    w1t[idx] = w1[j * 512 + c];
  } else if (bx < 160) {                // w2 -> w2t[k][j2]
    int idx = (bx - 128) * 256 + t;     // 8192
    int k = idx >> 6, j2 = idx & 63;
    w2t[idx] = w2[j2 * 128 + k];
  } else if (bx < 176) {                // a_pre[b][j] = b1[j] + w1[j][256:512].audio[b]
    int b = bx - 160;
    au[t] = audio[b * 256 + t];
    __syncthreads();
    int w = t >> 6, l = t & 63;
    float a0 = au[l], a1 = au[l + 64], a2 = au[l + 128], a3 = au[l + 192];
    for (int jj = 0; jj < 32; ++jj) {
      int j = w * 32 + jj;
      const float* row = w1 + j * 512 + 256;
      float s = row[l] * a0 + row[l + 64] * a1 + row[l + 128] * a2 + row[l + 192] * a3;
      #pragma unroll
      for (int off = 32; off; off >>= 1) s += __shfl_xor(s, off);
      if (l == 0) a_pre[b * 128 + j] = s + b1[j];
    }
  } else {
    for (int i = t; i < 4096; i += 256) pool[i] = 0.0f;
    if (t == 0) { mm[0] = 0xFFFFFFFFu; mm[1] = 0u; }
  }
}

// ---------------- Kernel 2: fused MLP + mi + pooling ----------------
// Round-14: REGISTER-TILE theory. 7 rounds of 24-37% VALU traced to
// loads-per-FMA >= pipe capacity (uniform ds_read_b128 still writes back
// 16B x 64 lanes). Fix: 8x8 thread tile -> 0.25 loads/FMA (4 per-lane
// ds_read_b128 per 128 VALU cyc). Block = 64 pos x 128 j, 128 threads
// (2 waves), grid 49x16=784 = 3.06 blk/CU (LDS 50KB -> 3/CU). fm+w1
// double-buffered via global_load_lds, 32-k chunks (4096 cyc compute
// hides 900 cyc HBM; 1 barrier/chunk). GEMM2: h1f from LDS (aliased) +
// per-lane w2 float4 from global (32KB, L1-hot). LN: shfl over jg +
// 2-wave LDS combine.
__global__ __launch_bounds__(128) void mlp_kernel(
    const float* __restrict__ fm, const float* __restrict__ w1t,
    const float* __restrict__ w2t, const float* __restrict__ b2,
    const float* __restrict__ w3, const float* __restrict__ b3,
    const float* __restrict__ g1, const float* __restrict__ be1,
    const float* __restrict__ g2, const float* __restrict__ be2,
    const float* __restrict__ a_pre, float* __restrict__ mi_out,
    float* __restrict__ pool, unsigned* __restrict__ mm)
{
  // [A0 2048][A1 2048][B0 4096][B1 4096] floats; after GEMM1: h1f[128][64] at 0
  __shared__ __align__(16) float smem[12288];   // 48 KB
  __shared__ __align__(16) float red[2][2][64]; // [phase][wave][pos]
  __shared__ float miL[64];

  const int b  = blockIdx.y;
  const int s0 = blockIdx.x * 64;
  const int t  = threadIdx.x;
  const int l  = t & 63;
  const int w  = __builtin_amdgcn_readfirstlane(t >> 6);  // 0/1, uniform
  const int pg = l & 7;          // pos group: pos = pg*8 + ii
  const int jg = l >> 3;         // j group:   j = w*64 + jg*8 + jj

  const float* fmblk = fm + (size_t)b * 256 * HW + s0;

  auto stage = [&](int ch, int bd) {
    #pragma unroll
    for (int i = 0; i < 4; ++i) {     // A: [32k][64pos] 8KB, 4 rows/issue
      const float* g = fmblk + (size_t)(ch * 32 + (w * 4 + i) * 4 + (l >> 4)) * HW
                       + (l & 15) * 4;
      float* d = smem + bd * 2048 + (w * 4 + i) * 256;
      __builtin_amdgcn_global_load_lds(
          (const __attribute__((address_space(1))) void*)g,
          (__attribute__((address_space(3))) void*)d, 16, 0, 0);
    }
    #pragma unroll
    for (int i = 0; i < 8; ++i) {     // B: [32k][128j] 16KB, 2 rows/issue
      const float* g = w1t + (size_t)(ch * 32 + (w * 8 + i) * 2 + (l >> 5)) * 128
                       + (l & 31) * 4;
      float* d = smem + 4096 + bd * 4096 + (w * 8 + i) * 256;
      __builtin_amdgcn_global_load_lds(
          (const __attribute__((address_space(1))) void*)g,
          (__attribute__((address_space(3))) void*)d, 16, 0, 0);
    }
  };

  // ---- GEMM1: acc[ii][jj], pos = pg*8+ii, j = w*64+jg*8+jj, K=256 ----
  float acc[8][8];
  #pragma unroll
  for (int ii = 0; ii < 8; ++ii)
    #pragma unroll
    for (int jj = 0; jj < 8; ++jj) acc[ii][jj] = 0.f;

  stage(0, 0);
  __syncthreads();
  #pragma unroll 1
  for (int ch = 0; ch < 8; ++ch) {
    if (ch < 7) stage(ch + 1, (ch + 1) & 1);
    const float* Ab = smem + (ch & 1) * 2048;
    const float* Bb = smem + 4096 + (ch & 1) * 4096;
    #pragma unroll 4
    for (int k = 0; k < 32; ++k) {
      float4 a0 = *(const float4*)(Ab + k * 64 + pg * 8);
      float4 a1 = *(const float4*)(Ab + k * 64 + pg * 8 + 4);
      float4 b0 = *(const float4*)(Bb + k * 128 + w * 64 + jg * 8);
      float4 b1 = *(const float4*)(Bb + k * 128 + w * 64 + jg * 8 + 4);
      float av[8] = {a0.x, a0.y, a0.z, a0.w, a1.x, a1.y, a1.z, a1.w};
      float bv[8] = {b0.x, b0.y, b0.z, b0.w, b1.x, b1.y, b1.z, b1.w};
      #pragma unroll
      for (int ii = 0; ii < 8; ++ii)
        #pragma unroll
        for (int jj = 0; jj < 8; ++jj)
          acc[ii][jj] = fmaf(av[ii], bv[jj], acc[ii][jj]);
    }
    __syncthreads();
  }
  {   // bias + audio pre-projection (per j)
    const float* ap = a_pre + b * 128 + w * 64 + jg * 8;
    float4 a40 = *(const float4*)(ap);
    float4 a41 = *(const float4*)(ap + 4);
    float av[8] = {a40.x, a40.y, a40.z, a40.w, a41.x, a41.y, a41.z, a41.w};
    #pragma unroll
    for (int ii = 0; ii < 8; ++ii)
      #pragma unroll
      for (int jj = 0; jj < 8; ++jj) acc[ii][jj] += av[jj];
  }

  // ---- LN1 over j=128: in-thread 8 + shfl over jg + 2-wave LDS combine ----
  float mu[8], inv[8];
  {
    float s[8];
    #pragma unroll
    for (int ii = 0; ii < 8; ++ii) {
      float v = 0.f;
      #pragma unroll
      for (int jj = 0; jj < 8; ++jj) v += acc[ii][jj];
      v += __shfl_xor(v, 8); v += __shfl_xor(v, 16); v += __shfl_xor(v, 32);
      s[ii] = v;
    }
    if (jg == 0) {
      *(float4*)&red[0][w][pg * 8]     = make_float4(s[0], s[1], s[2], s[3]);
      *(float4*)&red[0][w][pg * 8 + 4] = make_float4(s[4], s[5], s[6], s[7]);
    }
    __syncthreads();
    float4 rA0 = *(const float4*)&red[0][0][pg * 8];
    float4 rA1 = *(const float4*)&red[0][0][pg * 8 + 4];
    float4 rB0 = *(const float4*)&red[0][1][pg * 8];
    float4 rB1 = *(const float4*)&red[0][1][pg * 8 + 4];
    mu[0] = (rA0.x + rB0.x) * (1.0f/128.0f); mu[1] = (rA0.y + rB0.y) * (1.0f/128.0f);
    mu[2] = (rA0.z + rB0.z) * (1.0f/128.0f); mu[3] = (rA0.w + rB0.w) * (1.0f/128.0f);
    mu[4] = (rA1.x + rB1.x) * (1.0f/128.0f); mu[5] = (rA1.y + rB1.y) * (1.0f/128.0f);
    mu[6] = (rA1.z + rB1.z) * (1.0f/128.0f); mu[7] = (rA1.w + rB1.w) * (1.0f/128.0f);
    #pragma unroll
    for (int ii = 0; ii < 8; ++ii) {
      float v = 0.f;
      #pragma unroll
      for (int jj = 0; jj < 8; ++jj) { float d = acc[ii][jj] - mu[ii]; v = fmaf(d, d, v); }
      v += __shfl_xor(v, 8); v += __shfl_xor(v, 16); v += __shfl_xor(v, 32);
      s[ii] = v;
    }
    if (jg == 0) {
      *(float4*)&red[1][w][pg * 8]     = make_float4(s[0], s[1], s[2], s[3]);
      *(float4*)&red[1][w][pg * 8 + 4] = make_float4(s[4], s[5], s[6], s[7]);
    }
    __syncthreads();
    float4 vA0 = *(const float4*)&red[1][0][pg * 8];
    float4 vA1 = *(const float4*)&red[1][0][pg * 8 + 4];
    float4 vB0 = *(const float4*)&red[1][1][pg * 8];
    float4 vB1 = *(const float4*)&red[1][1][pg * 8 + 4];
    inv[0] = 1.0f / sqrtf((vA0.x + vB0.x) * (1.0f/128.0f) + 1e-5f);
    inv[1] = 1.0f / sqrtf((vA0.y + vB0.y) * (1.0f/128.0f) + 1e-5f);
    inv[2] = 1.0f / sqrtf((vA0.z + vB0.z) * (1.0f/128.0f) + 1e-5f);
    inv[3] = 1.0f / sqrtf((vA0.w + vB0.w) * (1.0f/128.0f) + 1e-5f);
    inv[4] = 1.0f / sqrtf((vA1.x + vB1.x) * (1.0f/128.0f) + 1e-5f);
    inv[5] = 1.0f / sqrtf((vA1.y + vB1.y) * (1.0f/128.0f) + 1e-5f);
    inv[6] = 1.0f / sqrtf((vA1.z + vB1.z) * (1.0f/128.0f) + 1e-5f);
    inv[7] = 1.0f / sqrtf((vA1.w + vB1.w) * (1.0f/128.0f) + 1e-5f);
  }

  // ---- spike -> h1f[j][pos] at smem[0..8192) (aliased over dbuf) ----
  {
    const float* gp = g1  + w * 64 + jg * 8;
    const float* bp = be1 + w * 64 + jg * 8;
    float4 g40 = *(const float4*)(gp), g41 = *(const float4*)(gp + 4);
    float4 b40 = *(const float4*)(bp), b41 = *(const float4*)(bp + 4);
    float gv[8] = {g40.x, g40.y, g40.z, g40.w, g41.x, g41.y, g41.z, g41.w};
    float bv[8] = {b40.x, b40.y, b40.z, b40.w, b41.x, b41.y, b41.z, b41.w};
    #pragma unroll
    for (int jj = 0; jj < 8; ++jj) {
      float4 h0, h1v;
      h0.x = spikef((acc[0][jj] - mu[0]) * inv[0] * gv[jj] + bv[jj]);
      h0.y = spikef((acc[1][jj] - mu[1]) * inv[1] * gv[jj] + bv[jj]);
      h0.z = spikef((acc[2][jj] - mu[2]) * inv[2] * gv[jj] + bv[jj]);
      h0.w = spikef((acc[3][jj] - mu[3]) * inv[3] * gv[jj] + bv[jj]);
      h1v.x = spikef((acc[4][jj] - mu[4]) * inv[4] * gv[jj] + bv[jj]);
      h1v.y = spikef((acc[5][jj] - mu[5]) * inv[5] * gv[jj] + bv[jj]);
      h1v.z = spikef((acc[6][jj] - mu[6]) * inv[6] * gv[jj] + bv[jj]);
      h1v.w = spikef((acc[7][jj] - mu[7]) * inv[7] * gv[jj] + bv[jj]);
      float* hrow = smem + (w * 64 + jg * 8 + jj) * 64 + pg * 8;
      *(float4*)(hrow) = h0;
      *(float4*)(hrow + 4) = h1v;
    }
  }
  __syncthreads();                       // h1f resident

  // ---- GEMM2: acc2[ii][jj], j2 = w*32+jg*4+jj, K2=128 ----
  float acc2[8][4];
  #pragma unroll
  for (int ii = 0; ii < 8; ++ii)
    #pragma unroll
    for (int jj = 0; jj < 4; ++jj) acc2[ii][jj] = 0.f;
  {
    const float* w2p = w2t + (w << 5) + (jg << 2);   // per-lane, L1/L2-hot
    #pragma unroll 4
    for (int k2 = 0; k2 < 128; ++k2) {
      float4 a0 = *(const float4*)(smem + k2 * 64 + pg * 8);
      float4 a1 = *(const float4*)(smem + k2 * 64 + pg * 8 + 4);
      float4 wv = *(const float4*)(w2p + (k2 << 6));
      float av[8] = {a0.x, a0.y, a0.z, a0.w, a1.x, a1.y, a1.z, a1.w};
      float bv[4] = {wv.x, wv.y, wv.z, wv.w};
      #pragma unroll
      for (int ii = 0; ii < 8; ++ii)
        #pragma unroll
        for (int jj = 0; jj < 4; ++jj)
          acc2[ii][jj] = fmaf(av[ii], bv[jj], acc2[ii][jj]);
    }
  }
  {
    float4 b4 = *(const float4*)(b2 + (w << 5) + (jg << 2));
    float bv[4] = {b4.x, b4.y, b4.z, b4.w};
    #pragma unroll
    for (int ii = 0; ii < 8; ++ii)
      #pragma unroll
      for (int jj = 0; jj < 4; ++jj) acc2[ii][jj] += bv[jj];
  }

  // ---- LN2 over j2=64 + spike + mi ----
  float mi[8];
  {
    float s[8], mu2[8], inv2[8];
    #pragma unroll
    for (int ii = 0; ii < 8; ++ii) {
      float v = acc2[ii][0] + acc2[ii][1] + acc2[ii][2] + acc2[ii][3];
      v += __shfl_xor(v, 8); v += __shfl_xor(v, 16); v += __shfl_xor(v, 32);
      s[ii] = v;
    }
    if (jg == 0) {
      *(float4*)&red[0][w][pg * 8]     = make_float4(s[0], s[1], s[2], s[3]);
      *(float4*)&red[0][w][pg * 8 + 4] = make_float4(s[4], s[5], s[6], s[7]);
    }
    __syncthreads();
    #pragma unroll
    for (int ii = 0; ii < 8; ++ii)
      mu2[ii] = (red[0][0][pg * 8 + ii] + red[0][1][pg * 8 + ii]) * (1.0f/64.0f);
    #pragma unroll
    for (int ii = 0; ii < 8; ++ii) {
      float v = 0.f;
      #pragma unroll
      for (int jj = 0; jj < 4; ++jj) { float d = acc2[ii][jj] - mu2[ii]; v = fmaf(d, d, v); }
      v += __shfl_xor(v, 8); v += __shfl_xor(v, 16); v += __shfl_xor(v, 32);
      s[ii] = v;
    }
    if (jg == 0) {
      *(float4*)&red[1][w][pg * 8]     = make_float4(s[0], s[1], s[2], s[3]);
      *(float4*)&red[1][w][pg * 8 + 4] = make_float4(s[4], s[5], s[6], s[7]);
    }
    __syncthreads();
    #pragma unroll
    for (int ii = 0; ii < 8; ++ii)
      inv2[ii] = 1.0f / sqrtf((red[1][0][pg * 8 + ii] + red[1][1][pg * 8 + ii])
                              * (1.0f/64.0f) + 1e-5f);
    float4 g4  = *(const float4*)(g2  + (w << 5) + (jg << 2));
    float4 be4 = *(const float4*)(be2 + (w << 5) + (jg << 2));
    float4 w34 = *(const float4*)(w3  + (w << 5) + (jg << 2));
    float gv[4] = {g4.x, g4.y, g4.z, g4.w};
    float bv[4] = {be4.x, be4.y, be4.z, be4.w};
    float wv[4] = {w34.x, w34.y, w34.z, w34.w};
    #pragma unroll
    for (int ii = 0; ii < 8; ++ii) {
      float p = 0.f;
      #pragma unroll
      for (int jj = 0; jj < 4; ++jj) {
        float sp = spikef((acc2[ii][jj] - mu2[ii]) * inv2[ii] * gv[jj] + bv[jj]);
        p = fmaf(sp, wv[jj], p);
      }
      p += __shfl_xor(p, 8); p += __shfl_xor(p, 16); p += __shfl_xor(p, 32);
      s[ii] = p;
    }
    if (jg == 0) {
      *(float4*)&red[0][w][pg * 8]     = make_float4(s[0], s[1], s[2], s[3]);
      *(float4*)&red[0][w][pg * 8 + 4] = make_float4(s[4], s[5], s[6], s[7]);
    }
    __syncthreads();
    const float b3v = b3[0];
    #pragma unroll
    for (int ii = 0; ii < 8; ++ii)
      mi[ii] = red[0][0][pg * 8 + ii] + red[0][1][pg * 8 + ii] + b3v;
  }

  // ---- store mi + miL; global min/max ----
  if (w == 0 && jg == 0) {
    float* mo = mi_out + b * HW + s0 + pg * 8;
    *(float4*)(mo)     = make_float4(mi[0], mi[1], mi[2], mi[3]);
    *(float4*)(mo + 4) = make_float4(mi[4], mi[5], mi[6], mi[7]);
    *(float4*)&miL[pg * 8]     = make_float4(mi[0], mi[1], mi[2], mi[3]);
    *(float4*)&miL[pg * 8 + 4] = make_float4(mi[4], mi[5], mi[6], mi[7]);
  }
  {
    float mn = mi[0], mx = mi[0];
    #pragma unroll
    for (int ii = 1; ii < 8; ++ii) { mn = fminf(mn, mi[ii]); mx = fmaxf(mx, mi[ii]); }
    mn = fminf(mn, __shfl_xor(mn, 1)); mx = fmaxf(mx, __shfl_xor(mx, 1));
    mn = fminf(mn, __shfl_xor(mn, 2)); mx = fmaxf(mx, __shfl_xor(mx, 2));
    mn = fminf(mn, __shfl_xor(mn, 4)); mx = fmaxf(mx, __shfl_xor(mx, 4));
    if (t == 0) {
      unsigned kmn = fkey(mn), kmx = fkey(mx);
      volatile unsigned* vmm = (volatile unsigned*)mm;
      if (kmn < vmm[0]) atomicMin(&mm[0], kmn);
      if (kmx > vmm[1]) atomicMax(&mm[1], kmx);
    }
  }
  __syncthreads();                       // miL resident

  // ---- pooling: pool[b][c] += sum_pos mi[pos]*fm[b][c][pos], 128 c/wave ----
  {
    const float ml = miL[l];
    const float* fp2 = fmblk + l + (size_t)(w << 7) * HW;
    #pragma unroll 4
    for (int ci = 0; ci < 128; ++ci) {
      float v = fp2[(size_t)ci * HW] * ml;
      #pragma unroll
      for (int off = 32; off; off >>= 1) v += __shfl_xor(v, off);
      if (l == 0) atomicAdd(&pool[b * 256 + (w << 7) + ci], v);
    }
  }
}

// ---------------- Kernel 3: projection + LN + spike -> channel scale ----------------
__global__ __launch_bounds__(256) void scale_kernel(
    const float* __restrict__ pool, const float* __restrict__ pw,
    const float* __restrict__ pb, const float* __restrict__ pg,
    const float* __restrict__ pbeta, float* __restrict__ scale,
    const unsigned* __restrict__ mm, float* __restrict__ gpar)
{
  __shared__ float pl[256];
  __shared__ float xsh[256];
  __shared__ float rs[4], rs2[4];
  int b = blockIdx.x, t = threadIdx.x;
  pl[t] = pool[b*256 + t];
  __syncthreads();
  int w = t >> 6, l = t & 63;
  float p0 = pl[l], p1 = pl[l+64], p2 = pl[l+128], p3 = pl[l+192];
  for (int jj = 0; jj < 64; ++jj) {
    int j = w*64 + jj;
    const float* row = pw + j*256;
    float s = row[l]*p0 + row[l+64]*p1 + row[l+128]*p2 + row[l+192]*p3;
    #pragma unroll
    for (int off = 32; off; off >>= 1) s += __shfl_xor(s, off);
    if (l == 0) xsh[j] = s;
  }
  __syncthreads();
  float x = xsh[t] + pb[t];
  float s = x;
  #pragma unroll
  for (int off = 32; off; off >>= 1) s += __shfl_xor(s, off);
  if (l == 0) rs[w] = s;
  __syncthreads();
  float mu = (rs[0]+rs[1]+rs[2]+rs[3]) * (1.0f/256.0f);
  float d = x - mu;
  float s2 = d*d;
  #pragma unroll
  for (int off = 32; off; off >>= 1) s2 += __shfl_xor(s2, off);
  if (l == 0) rs2[w] = s2;
  __syncthreads();
  float var = (rs2[0]+rs2[1]+rs2[2]+rs2[3]) * (1.0f/256.0f);
  float v = d / sqrtf(var + 1e-5f) * pg[t] + pbeta[t];
  scale[b*256 + t] = spikef(v);
  if (b == 0 && t == 0) {
    float mn = funkey(mm[0]), mx = funkey(mm[1]);
    gpar[0] = mn;
    gpar[1] = mx - mn + 1e-6f;
  }
}

// ---------------- Kernel 4: fusion map + normalized mi map ----------------
__global__ __launch_bounds__(256) void fuse_kernel(
    const float4* __restrict__ fm4, const float* __restrict__ scale,
    const float4* __restrict__ mi4, const float* __restrict__ gpar,
    float4* __restrict__ out4, float4* __restrict__ mi4out)
{
  const int c = blockIdx.x, b = blockIdx.y, t = threadIdx.x;
  if (c < 256) {
    float s = scale[b * 256 + c];
    size_t base = ((size_t)b * 256 + c) * 784;
    #pragma unroll
    for (int i = 0; i < 3; ++i) {
      int idx = t + i * 256;
      float4 v = fm4[base + idx];
      out4[base + idx] = make_float4(v.x*s, v.y*s, v.z*s, v.w*s);
    }
    int idx = t + 768;
    if (idx < 784) {
      float4 v = fm4[base + idx];
      out4[base + idx] = make_float4(v.x*s, v.y*s, v.z*s, v.w*s);
    }
  } else {
    float gmin = gpar[0], den = gpar[1];
    size_t base = (size_t)b * 784;
    #pragma unroll
    for (int i = 0; i < 3; ++i) {
      int idx = t + i * 256;
      float4 v = mi4[base + idx];
      mi4out[base + idx] = make_float4((v.x-gmin)/den, (v.y-gmin)/den,
                                       (v.z-gmin)/den, (v.w-gmin)/den);
    }
    int idx = t + 768;
    if (idx < 784) {
      float4 v = mi4[base + idx];
      mi4out[base + idx] = make_float4((v.x-gmin)/den, (v.y-gmin)/den,
                                       (v.z-gmin)/den, (v.w-gmin)/den);
    }
  }
}

extern "C" void kernel_launch(void* const* d_in, const int* in_sizes, int n_in,
                              void* d_out, int out_size, void* d_ws, size_t ws_size,
                              hipStream_t stream)
{
  const float* fm    = (const float*)d_in[0];
  const float* audio = (const float*)d_in[1];
  const float* w1    = (const float*)d_in[2];
  const float* b1    = (const float*)d_in[3];
  const float* g1    = (const float*)d_in[4];
  const float* be1   = (const float*)d_in[5];
  const float* w2    = (const float*)d_in[6];
  const float* b2    = (const float*)d_in[7];
  const float* g2    = (const float*)d_in[8];
  const float* be2   = (const float*)d_in[9];
  const float* w3    = (const float*)d_in[10];
  const float* b3    = (const float*)d_in[11];
  const float* pw    = (const float*)d_in[12];
  const float* pb    = (const float*)d_in[13];
  const float* pg    = (const float*)d_in[14];
  const float* pbeta = (const float*)d_in[15];

  float* ws    = (float*)d_ws;
  float* a_pre = ws;               // 2048 floats
  float* pool  = ws + 2048;        // 4096
  float* scale = ws + 6144;        // 4096
  float* mi    = ws + 10240;       // 50176 (16B aligned)
  float* w1t   = ws + 60416;       // 32768  [k][j]
  float* w2t   = ws + 93184;       // 8192   [k][j2]
  unsigned* mm = (unsigned*)(ws + 101376);  // 2 keys
  float* gpar  = ws + 101378;      // gmin, denom

  float* out    = (float*)d_out;
  float* mi4out = out + NPOS;

  prep_kernel<<<177, 256, 0, stream>>>(audio, w1, b1, w2, a_pre, w1t, w2t,
                                       pool, mm);
  mlp_kernel<<<dim3(49, 16), 128, 0, stream>>>(fm, w1t, w2t, b2, w3, b3,
                                               g1, be1, g2, be2,
                                               a_pre, mi, pool, mm);
  scale_kernel<<<16, 256, 0, stream>>>(pool, pw, pb, pg, pbeta, scale, mm, gpar);
  fuse_kernel<<<dim3(257, 16), 256, 0, stream>>>((const float4*)fm, scale,
                                                 (const float4*)mi, gpar,
                                                 (float4*)out, (float4*)mi4out);
}

// Round 9
// 331.382 us; speedup vs baseline: 1.2514x; 1.2514x over previous
//
#include <hip/hip_runtime.h>

#define HW 3136
#define NPOS 12845056   // 16*256*3136

__device__ __forceinline__ unsigned fkey(float f) {
  unsigned u = __float_as_uint(f);
  return (u & 0x80000000u) ? ~u : (u | 0x80000000u);
}
__device__ __forceinline__ float funkey(unsigned u) {
  return __uint_as_float((u & 0x80000000u) ? (u & 0x7FFFFFFFu) : ~u);
}
__device__ __forceinline__ float spikef(float x) {
  return fminf(fmaxf(rintf(x), 0.0f), 4.0f);
}

// ---------------- Kernel 1: transposes + audio pre-projection + init ----------------
// w1t: [k 256][j 128]   w2t: [k2 128][j2 64]
__global__ __launch_bounds__(256) void prep_kernel(
    const float* __restrict__ audio, const float* __restrict__ w1,
    const float* __restrict__ b1, const float* __restrict__ w2,
    float* __restrict__ a_pre, float* __restrict__ w1t,
    float* __restrict__ w2t, float* __restrict__ pool,
    unsigned* __restrict__ mm)
{
  __shared__ float au[256];
  const int bx = blockIdx.x, t = threadIdx.x;
  if (bx < 128) {                       // w1 visual half -> w1t[k][j]
    int idx = bx * 256 + t;             // 32768
    int c = idx >> 7, j = idx & 127;
    w1t[idx] = w1[j * 512 + c];
  } else if (bx < 160) {                // w2 -> w2t[k][j2]
    int idx = (bx - 128) * 256 + t;     // 8192
    int k = idx >> 6, j2 = idx & 63;
    w2t[idx] = w2[j2 * 128 + k];
  } else if (bx < 176) {                // a_pre[b][j] = b1[j] + w1[j][256:512].audio[b]
    int b = bx - 160;
    au[t] = audio[b * 256 + t];
    __syncthreads();
    int w = t >> 6, l = t & 63;
    float a0 = au[l], a1 = au[l + 64], a2 = au[l + 128], a3 = au[l + 192];
    for (int jj = 0; jj < 32; ++jj) {
      int j = w * 32 + jj;
      const float* row = w1 + j * 512 + 256;
      float s = row[l] * a0 + row[l + 64] * a1 + row[l + 128] * a2 + row[l + 192] * a3;
      #pragma unroll
      for (int off = 32; off; off >>= 1) s += __shfl_xor(s, off);
      if (l == 0) a_pre[b * 128 + j] = s + b1[j];
    }
  } else {
    for (int i = t; i < 4096; i += 256) pool[i] = 0.0f;
    if (t == 0) { mm[0] = 0xFFFFFFFFu; mm[1] = 0u; }
  }
}

// ---------------- Kernel 2: fused MLP + mi + pooling ----------------
// Round-15 synthesis of the three proven-good pieces:
//  (1) round-0: BOTH operands LDS-staged (zero VMEM / zero s_load in k-loop);
//  (2) round-7: weights read as wave-UNIFORM ds_read_b128 (broadcast) -> LDS
//      data ~8cy per 32 VALU cy/wave, under the 128B/cy/CU ceiling (round-0's
//      per-lane reads were 1.5x over);
//  (3) round-2: 8-wave 512-thread blocks -> 24 waves/CU demand (grid caps
//      blocks/CU at 3.06; more waves/block is the only TLP lever).
// GEMM1: 8 waves x 16-j slices, lane = pos; fm chunk [32k][64pos] 8KB +
// w1 chunk [32k][128j] 16KB, both double-buffered via global_load_lds
// (wave-uniform dst + per-lane src). Per k: 1 ds_b32 (2-way, free) +
// 4 uniform ds_b128 + 16 FMA. GEMM2: lane=j2, wave=8-pos slice, per-lane
// w2 dword (L1-hot) + 2 uniform ds_b128 of h1; LN2 wave-local. 13 barriers,
// 52.3KB LDS -> 3 blocks/CU; __launch_bounds__(512,6) caps VGPR at 85.
__global__ __launch_bounds__(512, 6) void mlp_kernel(
    const float* __restrict__ fm, const float* __restrict__ w1t,
    const float* __restrict__ w2t, const float* __restrict__ b2,
    const float* __restrict__ w3, const float* __restrict__ b3,
    const float* __restrict__ g1, const float* __restrict__ be1,
    const float* __restrict__ g2, const float* __restrict__ be2,
    const float* __restrict__ a_pre, float* __restrict__ mi_out,
    float* __restrict__ pool, unsigned* __restrict__ mm)
{
  // floats: A dbuf [0,4096) = 2x[32k][64pos]; B dbuf [4096,12288) = 2x[32k][128j]
  // after GEMM1: h1f[128][64] aliased at [0,8192)
  __shared__ __align__(16) float smem[12288];   // 48 KB
  __shared__ float red[16][64];                 // 4 KB LN partials
  __shared__ float miL[64];

  const int b  = blockIdx.y;
  const int s0 = blockIdx.x * 64;
  const int t  = threadIdx.x;
  const int l  = t & 63;                                   // GEMM1: lane = pos
  const int wv = __builtin_amdgcn_readfirstlane(t >> 6);   // 0..7, uniform

  const float* fmblk = fm + (size_t)b * 256 * HW + s0;
  float* const h1f = smem;

  auto stage = [&](int ch, int bd) {
    // A: fm chunk [32k][64pos] 8KB; wave wv stages rows 4wv..4wv+3 (1 issue)
    {
      const float* g = fmblk + (size_t)(ch * 32 + wv * 4 + (l >> 4)) * HW
                       + (l & 15) * 4;
      float* d = smem + bd * 2048 + wv * 256;              // wave-uniform dst
      __builtin_amdgcn_global_load_lds(
          (const __attribute__((address_space(1))) void*)g,
          (__attribute__((address_space(3))) void*)d, 16, 0, 0);
    }
    // B: w1 chunk [32k][128j] 16KB; wave wv stages rows 4wv..4wv+3 (2 issues)
    #pragma unroll
    for (int i = 0; i < 2; ++i) {
      const float* g = w1t + (size_t)(ch * 32 + wv * 4 + i * 2 + (l >> 5)) * 128
                       + (l & 31) * 4;
      float* d = smem + 4096 + bd * 4096 + (wv * 4 + i * 2) * 128;
      __builtin_amdgcn_global_load_lds(
          (const __attribute__((address_space(1))) void*)g,
          (__attribute__((address_space(3))) void*)d, 16, 0, 0);
    }
  };

  // ---- GEMM1: acc[j] = sum_k fm[k][pos] * w1t[k][wv*16+j], K=256 ----
  float acc[16];
  #pragma unroll
  for (int j = 0; j < 16; ++j) acc[j] = 0.f;

  stage(0, 0);
  __syncthreads();
  #pragma unroll 1
  for (int ch = 0; ch < 8; ++ch) {
    if (ch < 7) stage(ch + 1, (ch + 1) & 1);
    const float* Ab = smem + (ch & 1) * 2048;
    const float* Bb = smem + 4096 + (ch & 1) * 4096 + wv * 16;
    #pragma unroll 4
    for (int k = 0; k < 32; ++k) {
      float x = Ab[k * 64 + l];                            // per-lane b32, free
      const float* wk = Bb + k * 128;
      float4 q0 = *(const float4*)(wk);                    // uniform broadcast
      float4 q1 = *(const float4*)(wk + 4);
      float4 q2 = *(const float4*)(wk + 8);
      float4 q3 = *(const float4*)(wk + 12);
      acc[ 0] = fmaf(x, q0.x, acc[ 0]); acc[ 1] = fmaf(x, q0.y, acc[ 1]);
      acc[ 2] = fmaf(x, q0.z, acc[ 2]); acc[ 3] = fmaf(x, q0.w, acc[ 3]);
      acc[ 4] = fmaf(x, q1.x, acc[ 4]); acc[ 5] = fmaf(x, q1.y, acc[ 5]);
      acc[ 6] = fmaf(x, q1.z, acc[ 6]); acc[ 7] = fmaf(x, q1.w, acc[ 7]);
      acc[ 8] = fmaf(x, q2.x, acc[ 8]); acc[ 9] = fmaf(x, q2.y, acc[ 9]);
      acc[10] = fmaf(x, q2.z, acc[10]); acc[11] = fmaf(x, q2.w, acc[11]);
      acc[12] = fmaf(x, q3.x, acc[12]); acc[13] = fmaf(x, q3.y, acc[13]);
      acc[14] = fmaf(x, q3.z, acc[14]); acc[15] = fmaf(x, q3.w, acc[15]);
    }
    __syncthreads();            // buf reads done; next stage's loads landed
  }
  {   // bias + audio pre-projection (uniform per j)
    const float4* ap = (const float4*)(a_pre + b * 128 + wv * 16);
    #pragma unroll
    for (int q = 0; q < 4; ++q) {
      float4 a4 = ap[q];
      acc[4*q+0] += a4.x; acc[4*q+1] += a4.y;
      acc[4*q+2] += a4.z; acc[4*q+3] += a4.w;
    }
  }

  // ---- LN1 over j=128 (16 in-thread + 8-way cross-wave) ----
  float mu, inv;
  {
    float s = 0.f;
    #pragma unroll
    for (int j = 0; j < 16; ++j) s += acc[j];
    red[wv][l] = s;
    __syncthreads();
    s = 0.f;
    #pragma unroll
    for (int q = 0; q < 8; ++q) s += red[q][l];
    mu = s * (1.0f/128.0f);
    float s2 = 0.f;
    #pragma unroll
    for (int j = 0; j < 16; ++j) { float d = acc[j] - mu; s2 = fmaf(d, d, s2); }
    red[8 + wv][l] = s2;
    __syncthreads();
    s2 = 0.f;
    #pragma unroll
    for (int q = 0; q < 8; ++q) s2 += red[8 + q][l];
    inv = 1.0f / sqrtf(s2 * (1.0f/128.0f) + 1e-5f);
  }

  // ---- spike -> h1f[j][pos] (aliased over A dbuf + B0) ----
  {
    const float* gp = g1  + wv * 16;
    const float* bp = be1 + wv * 16;
    #pragma unroll
    for (int j = 0; j < 16; ++j) {
      float h = spikef((acc[j] - mu) * inv * gp[j] + bp[j]);
      h1f[(wv * 16 + j) * 64 + l] = h;                     // 2-way bank, free
    }
  }
  __syncthreads();                                         // h1f resident

  // ---- GEMM2: lane = j2, wave = 8-pos slice ----
  // a2[p] = sum_k2 h1[k2][wv*8+p] * w2t[k2][l]
  float a2[8];
  #pragma unroll
  for (int p = 0; p < 8; ++p) a2[p] = 0.f;
  {
    const float* hrow = h1f + wv * 8;          // uniform
    const float* w2p  = w2t + l;               // per-lane, L1/L2-hot coalesced
    #pragma unroll 2
    for (int k2 = 0; k2 < 128; ++k2) {
      float wval = w2p[k2 * 64];               // 1 VMEM / k2
      const float* hk = hrow + k2 * 64;
      float4 x0 = *(const float4*)(hk);        // uniform broadcast
      float4 x1 = *(const float4*)(hk + 4);
      a2[0] = fmaf(x0.x, wval, a2[0]); a2[1] = fmaf(x0.y, wval, a2[1]);
      a2[2] = fmaf(x0.z, wval, a2[2]); a2[3] = fmaf(x0.w, wval, a2[3]);
      a2[4] = fmaf(x1.x, wval, a2[4]); a2[5] = fmaf(x1.y, wval, a2[5]);
      a2[6] = fmaf(x1.z, wval, a2[6]); a2[7] = fmaf(x1.w, wval, a2[7]);
    }
  }
  {
    const float b2l = b2[l];                   // per-lane (j2 = l)
    #pragma unroll
    for (int p = 0; p < 8; ++p) a2[p] += b2l;
  }

  // ---- LN2 over j2=64 (lane dim -> wave-local shfl trees) + spike + mi ----
  float miv[8];
  {
    const float g2l = g2[l], be2l = be2[l], w3l = w3[l];
    const float b3v = b3[0];
    #pragma unroll
    for (int p = 0; p < 8; ++p) {
      float s = a2[p];
      #pragma unroll
      for (int off = 32; off; off >>= 1) s += __shfl_xor(s, off);
      float mu2 = s * (1.0f/64.0f);
      float d = a2[p] - mu2;
      float s2 = d * d;
      #pragma unroll
      for (int off = 32; off; off >>= 1) s2 += __shfl_xor(s2, off);
      float inv2 = 1.0f / sqrtf(s2 * (1.0f/64.0f) + 1e-5f);
      float sp = spikef(d * inv2 * g2l + be2l) * w3l;
      #pragma unroll
      for (int off = 32; off; off >>= 1) sp += __shfl_xor(sp, off);
      miv[p] = sp + b3v;                       // uniform across lanes
    }
  }

  // ---- select lane's pos value (static), store mi + miL ----
  {
    float m = miv[0];
    #pragma unroll
    for (int p = 1; p < 8; ++p) m = (l == p) ? miv[p] : m;
    if (l < 8) {
      mi_out[b * HW + s0 + wv * 8 + l] = m;
      miL[wv * 8 + l] = m;
    }
  }
  __syncthreads();                             // miL resident

  // ---- global min/max (wave 0 over the block's 64 positions) ----
  if (wv == 0) {
    float v = miL[l];
    float mn = v, mx = v;
    #pragma unroll
    for (int off = 32; off; off >>= 1) {
      mn = fminf(mn, __shfl_xor(mn, off));
      mx = fmaxf(mx, __shfl_xor(mx, off));
    }
    if (l == 0) {
      unsigned kmn = fkey(mn), kmx = fkey(mx);
      volatile unsigned* vmm = (volatile unsigned*)mm;
      if (kmn < vmm[0]) atomicMin(&mm[0], kmn);
      if (kmx > vmm[1]) atomicMax(&mm[1], kmx);
    }
  }

  // ---- pooling: pool[b][c] += sum_pos mi[pos]*fm[b][c][pos], 32 c/wave ----
  {
    const float mval = miL[l];
    const float* fp2 = fmblk + l + (size_t)(wv << 5) * HW;
    #pragma unroll 4
    for (int ci = 0; ci < 32; ++ci) {
      float v = fp2[(size_t)ci * HW] * mval;
      #pragma unroll
      for (int off = 32; off; off >>= 1) v += __shfl_xor(v, off);
      if (l == 0) atomicAdd(&pool[b * 256 + (wv << 5) + ci], v);
    }
  }
}

// ---------------- Kernel 3: projection + LN + spike -> channel scale ----------------
__global__ __launch_bounds__(256) void scale_kernel(
    const float* __restrict__ pool, const float* __restrict__ pw,
    const float* __restrict__ pb, const float* __restrict__ pg,
    const float* __restrict__ pbeta, float* __restrict__ scale,
    const unsigned* __restrict__ mm, float* __restrict__ gpar)
{
  __shared__ float pl[256];
  __shared__ float xsh[256];
  __shared__ float rs[4], rs2[4];
  int b = blockIdx.x, t = threadIdx.x;
  pl[t] = pool[b*256 + t];
  __syncthreads();
  int w = t >> 6, l = t & 63;
  float p0 = pl[l], p1 = pl[l+64], p2 = pl[l+128], p3 = pl[l+192];
  for (int jj = 0; jj < 64; ++jj) {
    int j = w*64 + jj;
    const float* row = pw + j*256;
    float s = row[l]*p0 + row[l+64]*p1 + row[l+128]*p2 + row[l+192]*p3;
    #pragma unroll
    for (int off = 32; off; off >>= 1) s += __shfl_xor(s, off);
    if (l == 0) xsh[j] = s;
  }
  __syncthreads();
  float x = xsh[t] + pb[t];
  float s = x;
  #pragma unroll
  for (int off = 32; off; off >>= 1) s += __shfl_xor(s, off);
  if (l == 0) rs[w] = s;
  __syncthreads();
  float mu = (rs[0]+rs[1]+rs[2]+rs[3]) * (1.0f/256.0f);
  float d = x - mu;
  float s2 = d*d;
  #pragma unroll
  for (int off = 32; off; off >>= 1) s2 += __shfl_xor(s2, off);
  if (l == 0) rs2[w] = s2;
  __syncthreads();
  float var = (rs2[0]+rs2[1]+rs2[2]+rs2[3]) * (1.0f/256.0f);
  float v = d / sqrtf(var + 1e-5f) * pg[t] + pbeta[t];
  scale[b*256 + t] = spikef(v);
  if (b == 0 && t == 0) {
    float mn = funkey(mm[0]), mx = funkey(mm[1]);
    gpar[0] = mn;
    gpar[1] = mx - mn + 1e-6f;
  }
}

// ---------------- Kernel 4: fusion map + normalized mi map ----------------
__global__ __launch_bounds__(256) void fuse_kernel(
    const float4* __restrict__ fm4, const float* __restrict__ scale,
    const float4* __restrict__ mi4, const float* __restrict__ gpar,
    float4* __restrict__ out4, float4* __restrict__ mi4out)
{
  const int c = blockIdx.x, b = blockIdx.y, t = threadIdx.x;
  if (c < 256) {
    float s = scale[b * 256 + c];
    size_t base = ((size_t)b * 256 + c) * 784;
    #pragma unroll
    for (int i = 0; i < 3; ++i) {
      int idx = t + i * 256;
      float4 v = fm4[base + idx];
      out4[base + idx] = make_float4(v.x*s, v.y*s, v.z*s, v.w*s);
    }
    int idx = t + 768;
    if (idx < 784) {
      float4 v = fm4[base + idx];
      out4[base + idx] = make_float4(v.x*s, v.y*s, v.z*s, v.w*s);
    }
  } else {
    float gmin = gpar[0], den = gpar[1];
    size_t base = (size_t)b * 784;
    #pragma unroll
    for (int i = 0; i < 3; ++i) {
      int idx = t + i * 256;
      float4 v = mi4[base + idx];
      mi4out[base + idx] = make_float4((v.x-gmin)/den, (v.y-gmin)/den,
                                       (v.z-gmin)/den, (v.w-gmin)/den);
    }
    int idx = t + 768;
    if (idx < 784) {
      float4 v = mi4[base + idx];
      mi4out[base + idx] = make_float4((v.x-gmin)/den, (v.y-gmin)/den,
                                       (v.z-gmin)/den, (v.w-gmin)/den);
    }
  }
}

extern "C" void kernel_launch(void* const* d_in, const int* in_sizes, int n_in,
                              void* d_out, int out_size, void* d_ws, size_t ws_size,
                              hipStream_t stream)
{
  const float* fm    = (const float*)d_in[0];
  const float* audio = (const float*)d_in[1];
  const float* w1    = (const float*)d_in[2];
  const float* b1    = (const float*)d_in[3];
  const float* g1    = (const float*)d_in[4];
  const float* be1   = (const float*)d_in[5];
  const float* w2    = (const float*)d_in[6];
  const float* b2    = (const float*)d_in[7];
  const float* g2    = (const float*)d_in[8];
  const float* be2   = (const float*)d_in[9];
  const float* w3    = (const float*)d_in[10];
  const float* b3    = (const float*)d_in[11];
  const float* pw    = (const float*)d_in[12];
  const float* pb    = (const float*)d_in[13];
  const float* pg    = (const float*)d_in[14];
  const float* pbeta = (const float*)d_in[15];

  float* ws    = (float*)d_ws;
  float* a_pre = ws;               // 2048 floats
  float* pool  = ws + 2048;        // 4096
  float* scale = ws + 6144;        // 4096
  float* mi    = ws + 10240;       // 50176 (16B aligned)
  float* w1t   = ws + 60416;       // 32768  [k][j]
  float* w2t   = ws + 93184;       // 8192   [k][j2]
  unsigned* mm = (unsigned*)(ws + 101376);  // 2 keys
  float* gpar  = ws + 101378;      // gmin, denom

  float* out    = (float*)d_out;
  float* mi4out = out + NPOS;

  prep_kernel<<<177, 256, 0, stream>>>(audio, w1, b1, w2, a_pre, w1t, w2t,
                                       pool, mm);
  mlp_kernel<<<dim3(49, 16), 512, 0, stream>>>(fm, w1t, w2t, b2, w3, b3,
                                               g1, be1, g2, be2,
                                               a_pre, mi, pool, mm);
  scale_kernel<<<16, 256, 0, stream>>>(pool, pw, pb, pg, pbeta, scale, mm, gpar);
  fuse_kernel<<<dim3(257, 16), 256, 0, stream>>>((const float4*)fm, scale,
                                                 (const float4*)mi, gpar,
                                                 (float4*)out, (float4*)mi4out);
}